// Round 2
// baseline (191.775 us; speedup 1.0000x reference)
//
#include <hip/hip_runtime.h>
#include <stdint.h>

// Problem constants: B=2, T=512, P=8, D=1024, NH=16, NKV=4, HD=64
// Rows (b,p,t): 16*512 = 8192.

typedef __attribute__((ext_vector_type(8))) short bf16x8;
typedef __attribute__((ext_vector_type(4))) float f32x4;
typedef __attribute__((ext_vector_type(16))) float f32x16;
typedef __attribute__((ext_vector_type(4))) unsigned short us4;
typedef __attribute__((ext_vector_type(8))) unsigned short us8;

static __device__ __forceinline__ unsigned short f2bf(float f) {
  unsigned u = __float_as_uint(f);
  u += 0x7fffu + ((u >> 16) & 1u);   // RNE
  return (unsigned short)(u >> 16);
}

static __device__ __forceinline__ void ld_lds16(const void* g, void* l) {
  __builtin_amdgcn_global_load_lds(
      (const __attribute__((address_space(1))) void*)g,
      (__attribute__((address_space(3))) void*)l, 16, 0, 0);
}

static __device__ __forceinline__ f32x4 mfma16(bf16x8 a, bf16x8 b, f32x4 c) {
  return __builtin_amdgcn_mfma_f32_16x16x32_bf16(a, b, c, 0, 0, 0);
}
static __device__ __forceinline__ f32x16 mfma32(bf16x8 a, bf16x8 b, f32x16 c) {
  return __builtin_amdgcn_mfma_f32_32x32x16_bf16(a, b, c, 0, 0, 0);
}

// ---- fused conversions: blocks 0..8191 pack x; 8192..8831 transpose W ----
__global__ __launch_bounds__(256) void conv_all(
    const float* __restrict__ hs, const float* __restrict__ Wq,
    const float* __restrict__ Wk, const float* __restrict__ Wv,
    const float* __restrict__ Wo, unsigned short* __restrict__ xb,
    unsigned short* __restrict__ wqkv, unsigned short* __restrict__ wot) {
  __shared__ float tile[64][65];
  int bid = blockIdx.x, tid = threadIdx.x;
  if (bid < 8192) {
    int gid = bid * 256 + tid;
    size_t e = (size_t)gid * 4;
    int r = (int)(e >> 10);          // bp*512 + t
    int d = (int)(e & 1023);
    int b = r >> 12, p = (r >> 9) & 7, t = r & 511;
    const float4* src = (const float4*)(hs + ((((size_t)b * 512 + t) * 8 + p) << 10) + d);
    float4 v = *src;
    us4 o;
    o.x = f2bf(v.x); o.y = f2bf(v.y); o.z = f2bf(v.z); o.w = f2bf(v.w);
    *(us4*)(xb + e) = o;
    return;
  }
  int tb = bid - 8192;
  const float* W; unsigned short* Wt; int N, tc0, tn0;
  if (tb < 256)      { W = Wq; Wt = wqkv;                       N = 1024; tc0 = (tb >> 4) * 64;          tn0 = (tb & 15) * 64; }
  else if (tb < 320) { W = Wk; Wt = wqkv + (size_t)1024 * 1024; N = 256;  tc0 = ((tb - 256) >> 2) * 64;  tn0 = ((tb - 256) & 3) * 64; }
  else if (tb < 384) { W = Wv; Wt = wqkv + (size_t)1280 * 1024; N = 256;  tc0 = ((tb - 320) >> 2) * 64;  tn0 = ((tb - 320) & 3) * 64; }
  else               { W = Wo; Wt = wot;                        N = 1024; tc0 = ((tb - 384) >> 4) * 64;  tn0 = ((tb - 384) & 15) * 64; }
  int tr = tid >> 4, tc = tid & 15;
#pragma unroll
  for (int i = 0; i < 4; ++i) {
    int c = tr + i * 16;
    float4 v = *(const float4*)(W + (size_t)(tc0 + c) * N + tn0 + tc * 4);
    tile[c][tc * 4 + 0] = v.x; tile[c][tc * 4 + 1] = v.y;
    tile[c][tc * 4 + 2] = v.z; tile[c][tc * 4 + 3] = v.w;
  }
  __syncthreads();
#pragma unroll
  for (int i = 0; i < 4; ++i) {
    int n = tr + i * 16;
    us4 o;
    o.x = f2bf(tile[tc * 4 + 0][n]); o.y = f2bf(tile[tc * 4 + 1][n]);
    o.z = f2bf(tile[tc * 4 + 2][n]); o.w = f2bf(tile[tc * 4 + 3][n]);
    *(us4*)(Wt + (size_t)(tn0 + n) * 1024 + tc0 + tc * 4) = o;
  }
}

// ---- 256x256x(K=1024) bf16 GEMM, 8-phase schedule (T2+T3+T4+T5) ---------
// 512 thr = 8 waves (2 wave-rows x 4 wave-cols), per-wave C = 128x64.
// Double-buffered LDS K-tiles (BK=64); per K-tile: 4 phases of
// {ds_read subtile; s_barrier; setprio(1); 16 MFMA; setprio(0); s_barrier},
// prefetch tile t+2 issued in phase 4, counted s_waitcnt vmcnt(8) (never 0
// in steady state) before the tile-boundary barrier. Raw s_barrier only —
// __syncthreads would re-insert the vmcnt(0) drain (the m97 ceiling).
// Swizzle: global chunk cg = schunk^row&7 pre-applied on src; readers use
// cgx = (quad+kk/8)^(row&7). Same proven scheme as the 128-tile kernel.
// MODE 0, NT=6: tn 0..3 -> qb (RoPE, *0.125); tn 4 -> kb (RoPE);
//               tn 5 -> vtb transposed ((bp,kvh,d),t) via LDS transpose.
// MODE 1, NT=4: fp32 out[(b,t,p),col].
template <int NT, int MODE>
__global__ __launch_bounds__(512, 2) void gemm256(
    const unsigned short* __restrict__ A, const unsigned short* __restrict__ Bt,
    unsigned short* __restrict__ qb, unsigned short* __restrict__ kb,
    unsigned short* __restrict__ vtb, float* __restrict__ out) {
  constexpr int K = 1024;
  constexpr int KT = K / 64;                       // 16 K-tiles
  __shared__ __align__(16) unsigned short Sm[2][2][256 * 64];  // [buf][A|B]
  unsigned short* Cs = &Sm[0][0][0];               // epilogue reuse, 128 KiB

  int tid = threadIdx.x;
  int lane = tid & 63, wid = tid >> 6;
  int quad = lane >> 4, lo = lane & 15;
  int tn = blockIdx.x % NT, tm = blockIdx.x / NT;
  int wr = wid >> 2, wc = wid & 3;
  int srow = lane >> 3, schunk = lane & 7;
  int cg = schunk ^ srow;

  const unsigned short* pa = A + ((size_t)(tm * 256) + wid * 8 + srow) * K + cg * 8;
  const unsigned short* pb = Bt + ((size_t)(tn * 256) + wid * 8 + srow) * K + cg * 8;

  f32x4 z = {0.f, 0.f, 0.f, 0.f};
  f32x4 acc[8][4];
#pragma unroll
  for (int i = 0; i < 8; ++i)
#pragma unroll
    for (int j = 0; j < 4; ++j) acc[i][j] = z;

  auto stage = [&](int t, int p) {
#pragma unroll
    for (int i = 0; i < 4; ++i) {
      ld_lds16(pa + (size_t)i * 64 * K + t * 64,
               (char*)&Sm[p][0][0] + (wid * 8 + i * 64) * 128);
      ld_lds16(pb + (size_t)i * 64 * K + t * 64,
               (char*)&Sm[p][1][0] + (wid * 8 + i * 64) * 128);
    }
  };

  stage(0, 0);
  stage(1, 1);
  asm volatile("s_waitcnt vmcnt(8)" ::: "memory");   // tile 0 landed
  asm volatile("s_barrier" ::: "memory");

  bf16x8 af[4][2], bb0[2][2], bb1[2][2];

  for (int t = 0; t < KT; ++t) {
    int p = t & 1;
    const unsigned short* As = &Sm[p][0][0];
    const unsigned short* Bs = &Sm[p][1][0];

    // ---- P1: read af half0 (8) + bb half0 (4); MFMA quadrant (m0,n0) ----
#pragma unroll
    for (int mi = 0; mi < 4; ++mi)
#pragma unroll
      for (int kx = 0; kx < 2; ++kx) {
        int row = wr * 128 + mi * 16 + lo;
        int cgx = (quad + kx * 4) ^ (row & 7);
        af[mi][kx] = *(const bf16x8*)(As + (size_t)row * 64 + cgx * 8);
      }
#pragma unroll
    for (int ni = 0; ni < 2; ++ni)
#pragma unroll
      for (int kx = 0; kx < 2; ++kx) {
        int row = wc * 64 + ni * 16 + lo;
        int cgx = (quad + kx * 4) ^ (row & 7);
        bb0[ni][kx] = *(const bf16x8*)(Bs + (size_t)row * 64 + cgx * 8);
      }
    asm volatile("s_barrier" ::: "memory");
    __builtin_amdgcn_s_setprio(1);
#pragma unroll
    for (int kx = 0; kx < 2; ++kx)
#pragma unroll
      for (int mi = 0; mi < 4; ++mi)
#pragma unroll
        for (int ni = 0; ni < 2; ++ni)
          acc[mi][ni] = mfma16(af[mi][kx], bb0[ni][kx], acc[mi][ni]);
    __builtin_amdgcn_s_setprio(0);
    asm volatile("s_barrier" ::: "memory");

    // ---- P2: read bb half1 (4); MFMA quadrant (m0,n1) -------------------
#pragma unroll
    for (int ni = 0; ni < 2; ++ni)
#pragma unroll
      for (int kx = 0; kx < 2; ++kx) {
        int row = wc * 64 + (ni + 2) * 16 + lo;
        int cgx = (quad + kx * 4) ^ (row & 7);
        bb1[ni][kx] = *(const bf16x8*)(Bs + (size_t)row * 64 + cgx * 8);
      }
    asm volatile("s_barrier" ::: "memory");
    __builtin_amdgcn_s_setprio(1);
#pragma unroll
    for (int kx = 0; kx < 2; ++kx)
#pragma unroll
      for (int mi = 0; mi < 4; ++mi)
#pragma unroll
        for (int ni = 0; ni < 2; ++ni)
          acc[mi][ni + 2] = mfma16(af[mi][kx], bb1[ni][kx], acc[mi][ni + 2]);
    __builtin_amdgcn_s_setprio(0);
    asm volatile("s_barrier" ::: "memory");

    // ---- P3: read af half1 (8, overwrite); MFMA quadrant (m1,n1) --------
#pragma unroll
    for (int mi = 0; mi < 4; ++mi)
#pragma unroll
      for (int kx = 0; kx < 2; ++kx) {
        int row = wr * 128 + 64 + mi * 16 + lo;
        int cgx = (quad + kx * 4) ^ (row & 7);
        af[mi][kx] = *(const bf16x8*)(As + (size_t)row * 64 + cgx * 8);
      }
    asm volatile("s_barrier" ::: "memory");
    __builtin_amdgcn_s_setprio(1);
#pragma unroll
    for (int kx = 0; kx < 2; ++kx)
#pragma unroll
      for (int mi = 0; mi < 4; ++mi)
#pragma unroll
        for (int ni = 0; ni < 2; ++ni)
          acc[mi + 4][ni + 2] = mfma16(af[mi][kx], bb1[ni][kx], acc[mi + 4][ni + 2]);
    __builtin_amdgcn_s_setprio(0);
    asm volatile("s_barrier" ::: "memory");

    // ---- P4: prefetch tile t+2 into buf p; MFMA quadrant (m1,n0);
    //          counted vmcnt for tile t+1; tile-boundary barrier ----------
    bool pf = (t + 2 < KT);
    if (pf) stage(t + 2, p);
    __builtin_amdgcn_s_setprio(1);
#pragma unroll
    for (int kx = 0; kx < 2; ++kx)
#pragma unroll
      for (int mi = 0; mi < 4; ++mi)
#pragma unroll
        for (int ni = 0; ni < 2; ++ni)
          acc[mi + 4][ni] = mfma16(af[mi][kx], bb0[ni][kx], acc[mi + 4][ni]);
    __builtin_amdgcn_s_setprio(0);
    if (pf) asm volatile("s_waitcnt vmcnt(8)" ::: "memory");
    else    asm volatile("s_waitcnt vmcnt(0)" ::: "memory");
    asm volatile("s_barrier" ::: "memory");
  }

  // ---- epilogue: C/D frag layout col = lane&15, row = quad*4 + r --------
  if (MODE == 0 && tn < 5) {
    float qscale = (tn < 4) ? 0.125f : 1.0f;       // fold 1/sqrt(HD) into Q
#pragma unroll
    for (int mi = 0; mi < 8; ++mi)
#pragma unroll
      for (int r = 0; r < 4; ++r) {
        int row = wr * 128 + mi * 16 + quad * 4 + r;
        int tpos = (tm * 256 + row) & 511;
#pragma unroll
        for (int ni = 0; ni < 2; ++ni) {
          float invf = exp2f((float)(ni * 16 + lo) * -0.41524101186092029f);
          float ang = (float)tpos * invf;
          float s, c;
          __sincosf(ang, &s, &c);
          float x1 = acc[mi][ni][r], x2 = acc[mi][ni + 2][r];
          acc[mi][ni][r]     = (x1 * c - x2 * s) * qscale;
          acc[mi][ni + 2][r] = (x1 * s + x2 * c) * qscale;
        }
      }
#pragma unroll
    for (int mi = 0; mi < 8; ++mi)
#pragma unroll
      for (int ni = 0; ni < 4; ++ni)
#pragma unroll
        for (int r = 0; r < 4; ++r) {
          int row = wr * 128 + mi * 16 + quad * 4 + r;
          int col = wc * 64 + ni * 16 + lo;
          int cs = col ^ (((row >> 2) & 3) << 3);
          Cs[row * 256 + cs] = f2bf(acc[mi][ni][r]);
        }
    __syncthreads();
    int tc = tid & 31, ro = tid >> 5;
#pragma unroll
    for (int it = 0; it < 16; ++it) {
      int row = ro + 16 * it;
      int cs = (tc * 8) ^ (((row >> 2) & 3) << 3);
      us8 v = *(const us8*)(Cs + row * 256 + cs);
      size_t grow = (size_t)(tm * 256 + row);
      if (tn < 4) *(us8*)(qb + grow * 1024 + tn * 256 + tc * 8) = v;
      else        *(us8*)(kb + grow * 256 + tc * 8) = v;
    }
  } else if (MODE == 0) {
    // V^T: stage transposed into Cs[col][t-local], then coalesced stores.
#pragma unroll
    for (int mi = 0; mi < 8; ++mi)
#pragma unroll
      for (int ni = 0; ni < 4; ++ni)
#pragma unroll
        for (int r = 0; r < 4; ++r) {
          int trow = wr * 128 + mi * 16 + quad * 4 + r;   // t-local 0..255
          int col = wc * 64 + ni * 16 + lo;               // c-local 0..255
          Cs[col * 256 + (trow ^ ((col & 7) << 3))] = f2bf(acc[mi][ni][r]);
        }
    __syncthreads();
    int t0 = (tid & 31) * 8, colIdx = tid >> 5;
    int bp = tm >> 1, tbase = (tm & 1) * 256;
#pragma unroll
    for (int it = 0; it < 16; ++it) {
      int col = colIdx + it * 16;
      us8 v = *(const us8*)(Cs + col * 256 + (t0 ^ ((col & 7) << 3)));
      int hh = col >> 6, dd = col & 63;
      *(us8*)(vtb + (((size_t)(bp * 4 + hh)) * 64 + dd) * 512 + tbase + t0) = v;
    }
  } else {
#pragma unroll
    for (int mi = 0; mi < 8; ++mi) {
      for (int ni = 0; ni < 4; ++ni) {
        int col = tn * 256 + wc * 64 + ni * 16 + lo;
        for (int r = 0; r < 4; ++r) {
          int grow = tm * 256 + wr * 128 + mi * 16 + quad * 4 + r;
          int bp = grow >> 9, tt = grow & 511;
          int b = bp >> 3, pp = bp & 7;
          out[((((size_t)b * 512 + tt) * 8 + pp) << 10) + col] = acc[mi][ni][r];
        }
      }
    }
  }
}

// ---- attention: transposed-S 32x32x16 MFMA, fixed-max softmax ------------
__global__ __launch_bounds__(256, 4) void attn(
    const unsigned short* __restrict__ qb, const unsigned short* __restrict__ kb,
    const unsigned short* __restrict__ vtb, unsigned short* __restrict__ ao) {
  __shared__ __align__(16) unsigned short Qs[128 * 64];
  __shared__ __align__(16) unsigned short Ks[64 * 64];
  __shared__ __align__(16) unsigned short Vs[64 * 64];   // V^T: [d][key]

  int tid = threadIdx.x;
  int lane = tid & 63, wid = tid >> 6;
  int lo32 = lane & 31, hl = lane >> 5;
  int qt = blockIdx.x & 3, bph = blockIdx.x >> 2;
  int head = bph & 15, bp = bph >> 4;
  int kvh = head >> 2;
  int t0 = qt * 128;
  int srow = lane >> 3, schunk = lane & 7;

  const unsigned short* qg = qb + ((size_t)(bp * 512 + t0)) * 1024 + head * 64;
  const unsigned short* kg = kb + ((size_t)bp * 512) * 256 + kvh * 64;
  const unsigned short* vg = vtb + ((size_t)(bp * 4 + kvh)) * 64 * 512;

  for (int i = 0; i < 4; ++i) {    // stage Q once: 128 rows x 128B
    int row = wid * 8 + i * 32 + srow;
    int cg = schunk ^ (row & 7);
    ld_lds16(qg + (size_t)row * 1024 + cg * 8, (char*)Qs + (wid * 8 + i * 32) * 128);
  }

  f32x16 z16 = {0.f};
  f32x16 o0 = z16, o1 = z16;
  float psum = 0.f;
  int qrow = wid * 32 + lo32;

  for (int kt = 0; kt < 512; kt += 64) {
    __syncthreads();
    for (int i = 0; i < 2; ++i) {  // stage 64 keys of K and V^T
      int row = wid * 8 + i * 32 + srow;
      int cg = schunk ^ (row & 7);
      ld_lds16(kg + (size_t)(kt + row) * 256 + cg * 8, (char*)Ks + (wid * 8 + i * 32) * 128);
      ld_lds16(vg + (size_t)row * 512 + kt + cg * 8, (char*)Vs + (wid * 8 + i * 32) * 128);
    }
    __syncthreads();

    // S^T = K . Q^T over d=64 (4 chunks of K=16)
    f32x16 st0 = z16, st1 = z16;
#pragma unroll
    for (int kkc = 0; kkc < 4; ++kkc) {
      int ch = 2 * kkc + hl;
      bf16x8 qf = *(const bf16x8*)(Qs + (size_t)qrow * 64 + ((ch ^ (qrow & 7)) * 8));
      bf16x8 kf0 = *(const bf16x8*)(Ks + (size_t)lo32 * 64 + ((ch ^ (lo32 & 7)) * 8));
      bf16x8 kf1 = *(const bf16x8*)(Ks + (size_t)(32 + lo32) * 64 + ((ch ^ (lo32 & 7)) * 8));
      st0 = mfma32(kf0, qf, st0);
      st1 = mfma32(kf1, qf, st1);
    }

    // exp (no max subtraction; scale pre-folded into Q), pack, PV
#pragma unroll
    for (int t = 0; t < 2; ++t) {
      const f32x16& stv = t ? st1 : st0;
      unsigned pk[8], xpk[8];
#pragma unroll
      for (int p = 0; p < 8; ++p) {
        float e0 = __expf(stv[2 * p]);
        float e1 = __expf(stv[2 * p + 1]);
        psum += e0 + e1;
        pk[p] = ((__float_as_uint(e0) + 0x8000u) >> 16) |
                ((__float_as_uint(e1) + 0x8000u) & 0xffff0000u);
      }
#pragma unroll
      for (int p = 0; p < 8; ++p) xpk[p] = (unsigned)__shfl_xor((int)pk[p], 32);
#pragma unroll
      for (int cc = 0; cc < 2; ++cc) {
        int o = cc * 4;
        union { unsigned u[4]; bf16x8 v; } af;
        if (hl == 0) {
          af.u[0] = pk[o];      af.u[1] = pk[o + 1];
          af.u[2] = xpk[o];     af.u[3] = xpk[o + 1];
        } else {
          af.u[0] = xpk[o + 2]; af.u[1] = xpk[o + 3];
          af.u[2] = pk[o + 2];  af.u[3] = pk[o + 3];
        }
        int vch = 2 * (t * 2 + cc) + hl;
        bf16x8 v0 = *(const bf16x8*)(Vs + (size_t)lo32 * 64 + ((vch ^ (lo32 & 7)) * 8));
        bf16x8 v1 = *(const bf16x8*)(Vs + (size_t)(32 + lo32) * 64 + ((vch ^ (lo32 & 7)) * 8));
        o0 = mfma32(af.v, v0, o0);
        o1 = mfma32(af.v, v1, o1);
      }
    }
  }

  // normalize and store: D layout col=lane&31=d, row q_r=(r&3)+8*(r>>2)+4*hl
  psum += __shfl_xor(psum, 32);
  float inv = 1.f / psum;          // lane holds inv for q = lo32
#pragma unroll
  for (int r = 0; r < 16; ++r) {
    int q_r = (r & 3) + 8 * (r >> 2) + 4 * hl;
    float sc = __shfl(inv, q_r);   // holder lane q_r (lo32=q_r)
    size_t grow = (size_t)(bp * 512 + t0 + wid * 32 + q_r);
    ao[grow * 1024 + head * 64 + lo32]      = f2bf(o0[r] * sc);
    ao[grow * 1024 + head * 64 + 32 + lo32] = f2bf(o1[r] * sc);
  }
}

extern "C" void kernel_launch(void* const* d_in, const int* in_sizes, int n_in,
                              void* d_out, int out_size, void* d_ws, size_t ws_size,
                              hipStream_t stream) {
  const float* hs = (const float*)d_in[0];
  const float* Wq = (const float*)d_in[1];
  const float* Wk = (const float*)d_in[2];
  const float* Wv = (const float*)d_in[3];
  const float* Wo = (const float*)d_in[4];
  float* out = (float*)d_out;

  unsigned short* xb   = (unsigned short*)d_ws;                 // 8192*1024
  unsigned short* wqkv = xb + (size_t)8192 * 1024;              // 1536*1024
  unsigned short* wot  = wqkv + (size_t)1536 * 1024;            // 1024*1024
  unsigned short* qbuf = wot + (size_t)1024 * 1024;             // 8192*1024
  unsigned short* kbuf = qbuf + (size_t)8192 * 1024;            // 8192*256
  unsigned short* vtb  = kbuf + (size_t)8192 * 256;             // 8192*256
  unsigned short* ao   = xb;                                    // alias

  conv_all<<<8832, 256, 0, stream>>>(hs, Wq, Wk, Wv, Wo, xb, wqkv, wot);
  gemm256<6, 0><<<192, 512, 0, stream>>>(xb, wqkv, qbuf, kbuf, vtb, nullptr);
  attn<<<1024, 256, 0, stream>>>(qbuf, kbuf, vtb, ao);
  gemm256<4, 1><<<128, 512, 0, stream>>>(ao, wot, nullptr, nullptr, nullptr, out);
}

// Round 3
// 179.534 us; speedup vs baseline: 1.0682x; 1.0682x over previous
//
#include <hip/hip_runtime.h>
#include <stdint.h>

// Problem constants: B=2, T=512, P=8, D=1024, NH=16, NKV=4, HD=64
// Rows (b,p,t): 16*512 = 8192.

typedef __attribute__((ext_vector_type(8))) short bf16x8;
typedef __attribute__((ext_vector_type(4))) float f32x4;
typedef __attribute__((ext_vector_type(16))) float f32x16;
typedef __attribute__((ext_vector_type(4))) unsigned short us4;
typedef __attribute__((ext_vector_type(8))) unsigned short us8;

static __device__ __forceinline__ unsigned short f2bf(float f) {
  unsigned u = __float_as_uint(f);
  u += 0x7fffu + ((u >> 16) & 1u);   // RNE
  return (unsigned short)(u >> 16);
}

static __device__ __forceinline__ void ld_lds16(const void* g, void* l) {
  __builtin_amdgcn_global_load_lds(
      (const __attribute__((address_space(1))) void*)g,
      (__attribute__((address_space(3))) void*)l, 16, 0, 0);
}

static __device__ __forceinline__ f32x4 mfma16(bf16x8 a, bf16x8 b, f32x4 c) {
  return __builtin_amdgcn_mfma_f32_16x16x32_bf16(a, b, c, 0, 0, 0);
}
static __device__ __forceinline__ f32x16 mfma32(bf16x8 a, bf16x8 b, f32x16 c) {
  return __builtin_amdgcn_mfma_f32_32x32x16_bf16(a, b, c, 0, 0, 0);
}

// ---- fused conversions: blocks 0..8191 pack x; 8192..8831 transpose W ----
__global__ __launch_bounds__(256) void conv_all(
    const float* __restrict__ hs, const float* __restrict__ Wq,
    const float* __restrict__ Wk, const float* __restrict__ Wv,
    const float* __restrict__ Wo, unsigned short* __restrict__ xb,
    unsigned short* __restrict__ wqkv, unsigned short* __restrict__ wot) {
  __shared__ float tile[64][65];
  int bid = blockIdx.x, tid = threadIdx.x;
  if (bid < 8192) {
    int gid = bid * 256 + tid;
    size_t e = (size_t)gid * 4;
    int r = (int)(e >> 10);          // bp*512 + t
    int d = (int)(e & 1023);
    int b = r >> 12, p = (r >> 9) & 7, t = r & 511;
    const float4* src = (const float4*)(hs + ((((size_t)b * 512 + t) * 8 + p) << 10) + d);
    float4 v = *src;
    us4 o;
    o.x = f2bf(v.x); o.y = f2bf(v.y); o.z = f2bf(v.z); o.w = f2bf(v.w);
    *(us4*)(xb + e) = o;
    return;
  }
  int tb = bid - 8192;
  const float* W; unsigned short* Wt; int N, tc0, tn0;
  if (tb < 256)      { W = Wq; Wt = wqkv;                       N = 1024; tc0 = (tb >> 4) * 64;          tn0 = (tb & 15) * 64; }
  else if (tb < 320) { W = Wk; Wt = wqkv + (size_t)1024 * 1024; N = 256;  tc0 = ((tb - 256) >> 2) * 64;  tn0 = ((tb - 256) & 3) * 64; }
  else if (tb < 384) { W = Wv; Wt = wqkv + (size_t)1280 * 1024; N = 256;  tc0 = ((tb - 320) >> 2) * 64;  tn0 = ((tb - 320) & 3) * 64; }
  else               { W = Wo; Wt = wot;                        N = 1024; tc0 = ((tb - 384) >> 4) * 64;  tn0 = ((tb - 384) & 15) * 64; }
  int tr = tid >> 4, tc = tid & 15;
#pragma unroll
  for (int i = 0; i < 4; ++i) {
    int c = tr + i * 16;
    float4 v = *(const float4*)(W + (size_t)(tc0 + c) * N + tn0 + tc * 4);
    tile[c][tc * 4 + 0] = v.x; tile[c][tc * 4 + 1] = v.y;
    tile[c][tc * 4 + 2] = v.z; tile[c][tc * 4 + 3] = v.w;
  }
  __syncthreads();
#pragma unroll
  for (int i = 0; i < 4; ++i) {
    int n = tr + i * 16;
    us4 o;
    o.x = f2bf(tile[tc * 4 + 0][n]); o.y = f2bf(tile[tc * 4 + 1][n]);
    o.z = f2bf(tile[tc * 4 + 2][n]); o.w = f2bf(tile[tc * 4 + 3][n]);
    *(us4*)(Wt + (size_t)(tn0 + n) * 1024 + tc0 + tc * 4) = o;
  }
}

// ---- 256x256x(K=1024) bf16 QKV GEMM, 8-phase schedule -------------------
// 512 thr = 8 waves (2x4), per-wave C = 128x64. Counters r2: 21.5% MfmaUtil
// at 75% grid fill => ~818 TF per active CU (= m248 full-stack rate). Grid
// is the limit (192 tiles), so keep 256^2 here; add T1 XCD swizzle for the
// 55MB over-fetch (A-panel sharers colocated per XCD L2).
// tn 0..3 -> qb (RoPE, *0.125); tn 4 -> kb (RoPE); tn 5 -> vtb transposed.
__global__ __launch_bounds__(512, 2) void gemm_qkv(
    const unsigned short* __restrict__ A, const unsigned short* __restrict__ Bt,
    unsigned short* __restrict__ qb, unsigned short* __restrict__ kb,
    unsigned short* __restrict__ vtb) {
  constexpr int K = 1024;
  constexpr int KT = K / 64;                       // 16 K-tiles
  __shared__ __align__(16) unsigned short Sm[2][2][256 * 64];  // [buf][A|B]
  unsigned short* Cs = &Sm[0][0][0];               // epilogue reuse, 128 KiB

  int tid = threadIdx.x;
  int lane = tid & 63, wid = tid >> 6;
  int quad = lane >> 4, lo = lane & 15;
  int wg = (blockIdx.x & 7) * 24 + (blockIdx.x >> 3);   // T1: 192 = 8 x 24
  int tn = wg % 6, tm = wg / 6;
  int wr = wid >> 2, wc = wid & 3;
  int srow = lane >> 3, schunk = lane & 7;
  int cg = schunk ^ srow;

  const unsigned short* pa = A + ((size_t)(tm * 256) + wid * 8 + srow) * K + cg * 8;
  const unsigned short* pb = Bt + ((size_t)(tn * 256) + wid * 8 + srow) * K + cg * 8;

  f32x4 z = {0.f, 0.f, 0.f, 0.f};
  f32x4 acc[8][4];
#pragma unroll
  for (int i = 0; i < 8; ++i)
#pragma unroll
    for (int j = 0; j < 4; ++j) acc[i][j] = z;

  auto stage = [&](int t, int p) {
#pragma unroll
    for (int i = 0; i < 4; ++i) {
      ld_lds16(pa + (size_t)i * 64 * K + t * 64,
               (char*)&Sm[p][0][0] + (wid * 8 + i * 64) * 128);
      ld_lds16(pb + (size_t)i * 64 * K + t * 64,
               (char*)&Sm[p][1][0] + (wid * 8 + i * 64) * 128);
    }
  };

  stage(0, 0);
  stage(1, 1);
  asm volatile("s_waitcnt vmcnt(8)" ::: "memory");   // tile 0 landed
  asm volatile("s_barrier" ::: "memory");

  bf16x8 af[4][2], bb0[2][2], bb1[2][2];

  for (int t = 0; t < KT; ++t) {
    int p = t & 1;
    const unsigned short* As = &Sm[p][0][0];
    const unsigned short* Bs = &Sm[p][1][0];

    // ---- P1: read af half0 + bb half0; MFMA quadrant (m0,n0) ------------
#pragma unroll
    for (int mi = 0; mi < 4; ++mi)
#pragma unroll
      for (int kx = 0; kx < 2; ++kx) {
        int row = wr * 128 + mi * 16 + lo;
        int cgx = (quad + kx * 4) ^ (row & 7);
        af[mi][kx] = *(const bf16x8*)(As + (size_t)row * 64 + cgx * 8);
      }
#pragma unroll
    for (int ni = 0; ni < 2; ++ni)
#pragma unroll
      for (int kx = 0; kx < 2; ++kx) {
        int row = wc * 64 + ni * 16 + lo;
        int cgx = (quad + kx * 4) ^ (row & 7);
        bb0[ni][kx] = *(const bf16x8*)(Bs + (size_t)row * 64 + cgx * 8);
      }
    asm volatile("s_barrier" ::: "memory");
    __builtin_amdgcn_s_setprio(1);
#pragma unroll
    for (int kx = 0; kx < 2; ++kx)
#pragma unroll
      for (int mi = 0; mi < 4; ++mi)
#pragma unroll
        for (int ni = 0; ni < 2; ++ni)
          acc[mi][ni] = mfma16(af[mi][kx], bb0[ni][kx], acc[mi][ni]);
    __builtin_amdgcn_s_setprio(0);
    asm volatile("s_barrier" ::: "memory");

    // ---- P2: read bb half1; MFMA quadrant (m0,n1) -----------------------
#pragma unroll
    for (int ni = 0; ni < 2; ++ni)
#pragma unroll
      for (int kx = 0; kx < 2; ++kx) {
        int row = wc * 64 + (ni + 2) * 16 + lo;
        int cgx = (quad + kx * 4) ^ (row & 7);
        bb1[ni][kx] = *(const bf16x8*)(Bs + (size_t)row * 64 + cgx * 8);
      }
    asm volatile("s_barrier" ::: "memory");
    __builtin_amdgcn_s_setprio(1);
#pragma unroll
    for (int kx = 0; kx < 2; ++kx)
#pragma unroll
      for (int mi = 0; mi < 4; ++mi)
#pragma unroll
        for (int ni = 0; ni < 2; ++ni)
          acc[mi][ni + 2] = mfma16(af[mi][kx], bb1[ni][kx], acc[mi][ni + 2]);
    __builtin_amdgcn_s_setprio(0);
    asm volatile("s_barrier" ::: "memory");

    // ---- P3: read af half1 (overwrite); MFMA quadrant (m1,n1) -----------
#pragma unroll
    for (int mi = 0; mi < 4; ++mi)
#pragma unroll
      for (int kx = 0; kx < 2; ++kx) {
        int row = wr * 128 + 64 + mi * 16 + lo;
        int cgx = (quad + kx * 4) ^ (row & 7);
        af[mi][kx] = *(const bf16x8*)(As + (size_t)row * 64 + cgx * 8);
      }
    asm volatile("s_barrier" ::: "memory");
    __builtin_amdgcn_s_setprio(1);
#pragma unroll
    for (int kx = 0; kx < 2; ++kx)
#pragma unroll
      for (int mi = 0; mi < 4; ++mi)
#pragma unroll
        for (int ni = 0; ni < 2; ++ni)
          acc[mi + 4][ni + 2] = mfma16(af[mi][kx], bb1[ni][kx], acc[mi + 4][ni + 2]);
    __builtin_amdgcn_s_setprio(0);
    asm volatile("s_barrier" ::: "memory");

    // ---- P4: prefetch t+2; MFMA quadrant (m1,n0); counted vmcnt ---------
    bool pf = (t + 2 < KT);
    if (pf) stage(t + 2, p);
    __builtin_amdgcn_s_setprio(1);
#pragma unroll
    for (int kx = 0; kx < 2; ++kx)
#pragma unroll
      for (int mi = 0; mi < 4; ++mi)
#pragma unroll
        for (int ni = 0; ni < 2; ++ni)
          acc[mi + 4][ni] = mfma16(af[mi][kx], bb0[ni][kx], acc[mi + 4][ni]);
    __builtin_amdgcn_s_setprio(0);
    if (pf) asm volatile("s_waitcnt vmcnt(8)" ::: "memory");
    else    asm volatile("s_waitcnt vmcnt(0)" ::: "memory");
    asm volatile("s_barrier" ::: "memory");
  }

  // ---- epilogue: C/D frag layout col = lane&15, row = quad*4 + r --------
  if (tn < 5) {
    float qscale = (tn < 4) ? 0.125f : 1.0f;       // fold 1/sqrt(HD) into Q
#pragma unroll
    for (int mi = 0; mi < 8; ++mi)
#pragma unroll
      for (int r = 0; r < 4; ++r) {
        int row = wr * 128 + mi * 16 + quad * 4 + r;
        int tpos = (tm * 256 + row) & 511;
#pragma unroll
        for (int ni = 0; ni < 2; ++ni) {
          float invf = exp2f((float)(ni * 16 + lo) * -0.41524101186092029f);
          float ang = (float)tpos * invf;
          float s, c;
          __sincosf(ang, &s, &c);
          float x1 = acc[mi][ni][r], x2 = acc[mi][ni + 2][r];
          acc[mi][ni][r]     = (x1 * c - x2 * s) * qscale;
          acc[mi][ni + 2][r] = (x1 * s + x2 * c) * qscale;
        }
      }
#pragma unroll
    for (int mi = 0; mi < 8; ++mi)
#pragma unroll
      for (int ni = 0; ni < 4; ++ni)
#pragma unroll
        for (int r = 0; r < 4; ++r) {
          int row = wr * 128 + mi * 16 + quad * 4 + r;
          int col = wc * 64 + ni * 16 + lo;
          int cs = col ^ (((row >> 2) & 3) << 3);
          Cs[row * 256 + cs] = f2bf(acc[mi][ni][r]);
        }
    __syncthreads();
    int tc = tid & 31, ro = tid >> 5;
#pragma unroll
    for (int it = 0; it < 16; ++it) {
      int row = ro + 16 * it;
      int cs = (tc * 8) ^ (((row >> 2) & 3) << 3);
      us8 v = *(const us8*)(Cs + row * 256 + cs);
      size_t grow = (size_t)(tm * 256 + row);
      if (tn < 4) *(us8*)(qb + grow * 1024 + tn * 256 + tc * 8) = v;
      else        *(us8*)(kb + grow * 256 + tc * 8) = v;
    }
  } else {
    // V^T: stage transposed into Cs[col][t-local], then coalesced stores.
#pragma unroll
    for (int mi = 0; mi < 8; ++mi)
#pragma unroll
      for (int ni = 0; ni < 4; ++ni)
#pragma unroll
        for (int r = 0; r < 4; ++r) {
          int trow = wr * 128 + mi * 16 + quad * 4 + r;   // t-local 0..255
          int col = wc * 64 + ni * 16 + lo;               // c-local 0..255
          Cs[col * 256 + (trow ^ ((col & 7) << 3))] = f2bf(acc[mi][ni][r]);
        }
    __syncthreads();
    int t0 = (tid & 31) * 8, colIdx = tid >> 5;
    int bp = tm >> 1, tbase = (tm & 1) * 256;
#pragma unroll
    for (int it = 0; it < 16; ++it) {
      int col = colIdx + it * 16;
      us8 v = *(const us8*)(Cs + col * 256 + (t0 ^ ((col & 7) << 3)));
      int hh = col >> 6, dd = col & 63;
      *(us8*)(vtb + (((size_t)(bp * 4 + hh)) * 64 + dd) * 512 + tbase + t0) = v;
    }
  }
}

// ---- 128x256x(K=1024) O-proj GEMM: 64x4 = 256 blocks = 100% grid fill ---
// r2 counters: old MODE1 ran 128 blocks = HALF the chip idle. 8 waves (2x4),
// per-wave C = 64x64 (acc 4x4). LDS: (128+256)x64x2B x 2buf = 96 KiB.
// Per K-tile: P1 {af+bb0 reads; 16 MFMA}, P2 {bb1 reads; 16 MFMA},
// P3 {prefetch t+2; counted vmcnt(6)} — prefetch is in its own phase after
// all tile-t ds_reads drained (no gload_lds-vs-undrained-ds_read race).
__global__ __launch_bounds__(512, 2) void gemm_o(
    const unsigned short* __restrict__ A, const unsigned short* __restrict__ Bt,
    float* __restrict__ out) {
  constexpr int K = 1024;
  constexpr int KT = K / 64;
  __shared__ __align__(16) unsigned short Sm[2][(128 + 256) * 64];

  int tid = threadIdx.x;
  int lane = tid & 63, wid = tid >> 6;
  int quad = lane >> 4, lo = lane & 15;
  int wg = (blockIdx.x & 7) * 32 + (blockIdx.x >> 3);   // T1: 256 = 8 x 32
  int tn = wg & 3, tm = wg >> 2;                        // tm 0..63, tn 0..3
  int wr = wid >> 2, wc = wid & 3;
  int srow = lane >> 3, schunk = lane & 7;
  int cg = schunk ^ srow;

  const unsigned short* pa = A + ((size_t)(tm * 128) + wid * 8 + srow) * K + cg * 8;
  const unsigned short* pb = Bt + ((size_t)(tn * 256) + wid * 8 + srow) * K + cg * 8;

  f32x4 z = {0.f, 0.f, 0.f, 0.f};
  f32x4 acc[4][4];
#pragma unroll
  for (int i = 0; i < 4; ++i)
#pragma unroll
    for (int j = 0; j < 4; ++j) acc[i][j] = z;

  auto stage = [&](int t, int p) {
    unsigned short* As = &Sm[p][0];
    unsigned short* Bs = &Sm[p][128 * 64];
#pragma unroll
    for (int i = 0; i < 2; ++i)
      ld_lds16(pa + (size_t)i * 64 * K + t * 64,
               (char*)As + (wid * 8 + i * 64) * 128);
#pragma unroll
    for (int i = 0; i < 4; ++i)
      ld_lds16(pb + (size_t)i * 64 * K + t * 64,
               (char*)Bs + (wid * 8 + i * 64) * 128);
  };

  stage(0, 0);
  stage(1, 1);
  asm volatile("s_waitcnt vmcnt(6)" ::: "memory");   // tile 0 landed
  asm volatile("s_barrier" ::: "memory");

  bf16x8 af[4][2], bb0[2][2], bb1[2][2];

  for (int t = 0; t < KT; ++t) {
    int p = t & 1;
    const unsigned short* As = &Sm[p][0];
    const unsigned short* Bs = &Sm[p][128 * 64];

    // ---- P1: af (all 4 m-frags) + bb half0; MFMA (n0,n1) ----------------
#pragma unroll
    for (int mi = 0; mi < 4; ++mi)
#pragma unroll
      for (int kx = 0; kx < 2; ++kx) {
        int row = wr * 64 + mi * 16 + lo;
        int cgx = (quad + kx * 4) ^ (row & 7);
        af[mi][kx] = *(const bf16x8*)(As + (size_t)row * 64 + cgx * 8);
      }
#pragma unroll
    for (int ni = 0; ni < 2; ++ni)
#pragma unroll
      for (int kx = 0; kx < 2; ++kx) {
        int row = wc * 64 + ni * 16 + lo;
        int cgx = (quad + kx * 4) ^ (row & 7);
        bb0[ni][kx] = *(const bf16x8*)(Bs + (size_t)row * 64 + cgx * 8);
      }
    asm volatile("s_barrier" ::: "memory");
    __builtin_amdgcn_s_setprio(1);
#pragma unroll
    for (int kx = 0; kx < 2; ++kx)
#pragma unroll
      for (int mi = 0; mi < 4; ++mi)
#pragma unroll
        for (int ni = 0; ni < 2; ++ni)
          acc[mi][ni] = mfma16(af[mi][kx], bb0[ni][kx], acc[mi][ni]);
    __builtin_amdgcn_s_setprio(0);
    asm volatile("s_barrier" ::: "memory");

    // ---- P2: bb half1; MFMA (n2,n3) -------------------------------------
#pragma unroll
    for (int ni = 0; ni < 2; ++ni)
#pragma unroll
      for (int kx = 0; kx < 2; ++kx) {
        int row = wc * 64 + (ni + 2) * 16 + lo;
        int cgx = (quad + kx * 4) ^ (row & 7);
        bb1[ni][kx] = *(const bf16x8*)(Bs + (size_t)row * 64 + cgx * 8);
      }
    asm volatile("s_barrier" ::: "memory");
    __builtin_amdgcn_s_setprio(1);
#pragma unroll
    for (int kx = 0; kx < 2; ++kx)
#pragma unroll
      for (int mi = 0; mi < 4; ++mi)
#pragma unroll
        for (int ni = 0; ni < 2; ++ni)
          acc[mi][ni + 2] = mfma16(af[mi][kx], bb1[ni][kx], acc[mi][ni + 2]);
    __builtin_amdgcn_s_setprio(0);
    asm volatile("s_barrier" ::: "memory");

    // ---- P3: prefetch t+2 (all tile-t reads drained); counted vmcnt -----
    bool pf = (t + 2 < KT);
    if (pf) {
      stage(t + 2, p);
      asm volatile("s_waitcnt vmcnt(6)" ::: "memory");
    } else {
      asm volatile("s_waitcnt vmcnt(0)" ::: "memory");
    }
    asm volatile("s_barrier" ::: "memory");
  }

  // ---- epilogue: fp32 out[(b,t,p),col]; 64B contiguous per quad ---------
#pragma unroll
  for (int mi = 0; mi < 4; ++mi) {
    for (int ni = 0; ni < 4; ++ni) {
      int col = tn * 256 + wc * 64 + ni * 16 + lo;
      for (int r = 0; r < 4; ++r) {
        int grow = tm * 128 + wr * 64 + mi * 16 + quad * 4 + r;
        int bp = grow >> 9, tt = grow & 511;
        int b = bp >> 3, pp = bp & 7;
        out[((((size_t)b * 512 + tt) * 8 + pp) << 10) + col] = acc[mi][ni][r];
      }
    }
  }
}

// ---- attention: transposed-S 32x32x16 MFMA, fixed-max softmax ------------
__global__ __launch_bounds__(256, 4) void attn(
    const unsigned short* __restrict__ qb, const unsigned short* __restrict__ kb,
    const unsigned short* __restrict__ vtb, unsigned short* __restrict__ ao) {
  __shared__ __align__(16) unsigned short Qs[128 * 64];
  __shared__ __align__(16) unsigned short Ks[64 * 64];
  __shared__ __align__(16) unsigned short Vs[64 * 64];   // V^T: [d][key]

  int tid = threadIdx.x;
  int lane = tid & 63, wid = tid >> 6;
  int lo32 = lane & 31, hl = lane >> 5;
  int wg = (blockIdx.x & 7) * 128 + (blockIdx.x >> 3);  // T1: 1024 = 8 x 128
  int qt = wg & 3, bph = wg >> 2;
  int head = bph & 15, bp = bph >> 4;
  int kvh = head >> 2;
  int t0 = qt * 128;
  int srow = lane >> 3, schunk = lane & 7;

  const unsigned short* qg = qb + ((size_t)(bp * 512 + t0)) * 1024 + head * 64;
  const unsigned short* kg = kb + ((size_t)bp * 512) * 256 + kvh * 64;
  const unsigned short* vg = vtb + ((size_t)(bp * 4 + kvh)) * 64 * 512;

  for (int i = 0; i < 4; ++i) {    // stage Q once: 128 rows x 128B
    int row = wid * 8 + i * 32 + srow;
    int cg = schunk ^ (row & 7);
    ld_lds16(qg + (size_t)row * 1024 + cg * 8, (char*)Qs + (wid * 8 + i * 32) * 128);
  }

  f32x16 z16 = {0.f};
  f32x16 o0 = z16, o1 = z16;
  float psum = 0.f;
  int qrow = wid * 32 + lo32;

  for (int kt = 0; kt < 512; kt += 64) {
    __syncthreads();
    for (int i = 0; i < 2; ++i) {  // stage 64 keys of K and V^T
      int row = wid * 8 + i * 32 + srow;
      int cg = schunk ^ (row & 7);
      ld_lds16(kg + (size_t)(kt + row) * 256 + cg * 8, (char*)Ks + (wid * 8 + i * 32) * 128);
      ld_lds16(vg + (size_t)row * 512 + kt + cg * 8, (char*)Vs + (wid * 8 + i * 32) * 128);
    }
    __syncthreads();

    // S^T = K . Q^T over d=64 (4 chunks of K=16)
    f32x16 st0 = z16, st1 = z16;
#pragma unroll
    for (int kkc = 0; kkc < 4; ++kkc) {
      int ch = 2 * kkc + hl;
      bf16x8 qf = *(const bf16x8*)(Qs + (size_t)qrow * 64 + ((ch ^ (qrow & 7)) * 8));
      bf16x8 kf0 = *(const bf16x8*)(Ks + (size_t)lo32 * 64 + ((ch ^ (lo32 & 7)) * 8));
      bf16x8 kf1 = *(const bf16x8*)(Ks + (size_t)(32 + lo32) * 64 + ((ch ^ (lo32 & 7)) * 8));
      st0 = mfma32(kf0, qf, st0);
      st1 = mfma32(kf1, qf, st1);
    }

    // exp (no max subtraction; scale pre-folded into Q), pack, PV
#pragma unroll
    for (int t = 0; t < 2; ++t) {
      const f32x16& stv = t ? st1 : st0;
      unsigned pk[8], xpk[8];
#pragma unroll
      for (int p = 0; p < 8; ++p) {
        float e0 = __expf(stv[2 * p]);
        float e1 = __expf(stv[2 * p + 1]);
        psum += e0 + e1;
        pk[p] = ((__float_as_uint(e0) + 0x8000u) >> 16) |
                ((__float_as_uint(e1) + 0x8000u) & 0xffff0000u);
      }
#pragma unroll
      for (int p = 0; p < 8; ++p) xpk[p] = (unsigned)__shfl_xor((int)pk[p], 32);
#pragma unroll
      for (int cc = 0; cc < 2; ++cc) {
        int o = cc * 4;
        union { unsigned u[4]; bf16x8 v; } af;
        if (hl == 0) {
          af.u[0] = pk[o];      af.u[1] = pk[o + 1];
          af.u[2] = xpk[o];     af.u[3] = xpk[o + 1];
        } else {
          af.u[0] = xpk[o + 2]; af.u[1] = xpk[o + 3];
          af.u[2] = pk[o + 2];  af.u[3] = pk[o + 3];
        }
        int vch = 2 * (t * 2 + cc) + hl;
        bf16x8 v0 = *(const bf16x8*)(Vs + (size_t)lo32 * 64 + ((vch ^ (lo32 & 7)) * 8));
        bf16x8 v1 = *(const bf16x8*)(Vs + (size_t)(32 + lo32) * 64 + ((vch ^ (lo32 & 7)) * 8));
        o0 = mfma32(af.v, v0, o0);
        o1 = mfma32(af.v, v1, o1);
      }
    }
  }

  // normalize and store: D layout col=lane&31=d, row q_r=(r&3)+8*(r>>2)+4*hl
  psum += __shfl_xor(psum, 32);
  float inv = 1.f / psum;          // lane holds inv for q = lo32
#pragma unroll
  for (int r = 0; r < 16; ++r) {
    int q_r = (r & 3) + 8 * (r >> 2) + 4 * hl;
    float sc = __shfl(inv, q_r);   // holder lane q_r (lo32=q_r)
    size_t grow = (size_t)(bp * 512 + t0 + wid * 32 + q_r);
    ao[grow * 1024 + head * 64 + lo32]      = f2bf(o0[r] * sc);
    ao[grow * 1024 + head * 64 + 32 + lo32] = f2bf(o1[r] * sc);
  }
}

extern "C" void kernel_launch(void* const* d_in, const int* in_sizes, int n_in,
                              void* d_out, int out_size, void* d_ws, size_t ws_size,
                              hipStream_t stream) {
  const float* hs = (const float*)d_in[0];
  const float* Wq = (const float*)d_in[1];
  const float* Wk = (const float*)d_in[2];
  const float* Wv = (const float*)d_in[3];
  const float* Wo = (const float*)d_in[4];
  float* out = (float*)d_out;

  unsigned short* xb   = (unsigned short*)d_ws;                 // 8192*1024
  unsigned short* wqkv = xb + (size_t)8192 * 1024;              // 1536*1024
  unsigned short* wot  = wqkv + (size_t)1536 * 1024;            // 1024*1024
  unsigned short* qbuf = wot + (size_t)1024 * 1024;             // 8192*1024
  unsigned short* kbuf = qbuf + (size_t)8192 * 1024;            // 8192*256
  unsigned short* vtb  = kbuf + (size_t)8192 * 256;             // 8192*256
  unsigned short* ao   = xb;                                    // alias

  conv_all<<<8832, 256, 0, stream>>>(hs, Wq, Wk, Wv, Wo, xb, wqkv, wot);
  gemm_qkv<<<192, 512, 0, stream>>>(xb, wqkv, qbuf, kbuf, vtb);
  attn<<<1024, 256, 0, stream>>>(qbuf, kbuf, vtb, ao);
  gemm_o<<<256, 512, 0, stream>>>(ao, wot, out);
}